// Round 8
// baseline (231.107 us; speedup 1.0000x reference)
//
#include <hip/hip_runtime.h>

#define NROW 513
#define NCOL 65
#define DD   64
#define NN   512
#define NLAYER 4
#define TOT  (NROW * NCOL)   // 33345

typedef float f32x16 __attribute__((ext_vector_type(16)));
typedef short s16x8  __attribute__((ext_vector_type(8)));

__device__ __forceinline__ short bf16_rne(float f) {
    unsigned u = __builtin_bit_cast(unsigned, f);
    u += 0x7FFFu + ((u >> 16) & 1u);
    return (short)(u >> 16);
}

// Math (per batch b): X = Z[:,:64] invariant, y = Z[:,64].
//   G = X[:512]^T X[:512] (bf16 MFMA), s1 = X[:512]^T y0[:512]
//   l: s = s1 + G u; rho = gamma_l rho + (q_l/512) s; u += alpha_l rho
//   out = Z with col64 = y0 + X u
// R7 structure: two kernels, no big LDS tile. L3 (256MB) holds Z (68MB), so
// the second read in kernel B is cheap; both kernels keep high occupancy.

// ---- Kernel A: per batch, G + s1 + recurrence -> u[b][64] in workspace ----
__global__ __launch_bounds__(512)
void kernA(const float* __restrict__ Zin,
           const float* __restrict__ allparam,
           const float* __restrict__ gam,
           const float* __restrict__ alp,
           float* __restrict__ uws) {
    __shared__ float yl[NN];
    __shared__ float Gl[DD][DD + 1];
    __shared__ float s1l[DD];
    __shared__ float ul[DD];
    __shared__ float qsl[NLAYER];

    const int tid  = threadIdx.x;
    const int w    = tid >> 6;          // 8 waves
    const int lane = tid & 63;
    const int half = lane >> 5;
    const int lc   = lane & 31;
    const long base = (long)blockIdx.x * TOT;

    for (int i = tid; i < DD * (DD + 1); i += 512) ((float*)Gl)[i] = 0.0f;
    if (tid < DD) { s1l[tid] = 0.0f; ul[tid] = 0.0f; }
    if (tid < NN) yl[tid] = Zin[base + (long)tid * NCOL + DD];
    if (tid < 64) {  // q_l = mean(diag(allparam[l,0,1]))
        for (int l = 0; l < NLAYER; ++l) {
            float vq = allparam[l * 8192 + 4096 + tid * 65];
            #pragma unroll
            for (int off = 32; off > 0; off >>= 1) vq += __shfl_down(vq, off, 64);
            if (tid == 0) qsl[l] = vq * (1.0f / 64.0f);
        }
    }
    __syncthreads();

    // G-MFMA + s1 partials: wave w handles K-rows [w*64, w*64+64)
    {
        f32x16 a00, a01, a10, a11;
        #pragma unroll
        for (int r = 0; r < 16; ++r) { a00[r] = 0.f; a01[r] = 0.f; a10[r] = 0.f; a11[r] = 0.f; }
        float sp0 = 0.f, sp1 = 0.f;

        #pragma unroll
        for (int s = 0; s < 4; ++s) {
            const int rbase = w * 64 + s * 16 + half * 8;
            s16x8 f0, f1;
            const float* rp = Zin + base + (long)rbase * NCOL + lc;
            #pragma unroll
            for (int e = 0; e < 8; ++e) {
                const float a0 = rp[0];            // col lc
                const float a1 = rp[32];           // col 32+lc
                const float yv = yl[rbase + e];
                sp0 += yv * a0;
                sp1 += yv * a1;
                f0[e] = bf16_rne(a0);
                f1[e] = bf16_rne(a1);
                rp += NCOL;
            }
            a00 = __builtin_amdgcn_mfma_f32_32x32x16_bf16(f0, f0, a00, 0, 0, 0);
            a01 = __builtin_amdgcn_mfma_f32_32x32x16_bf16(f0, f1, a01, 0, 0, 0);
            a10 = __builtin_amdgcn_mfma_f32_32x32x16_bf16(f1, f0, a10, 0, 0, 0);
            a11 = __builtin_amdgcn_mfma_f32_32x32x16_bf16(f1, f1, a11, 0, 0, 0);
        }

        sp0 += __shfl_xor(sp0, 32, 64);
        sp1 += __shfl_xor(sp1, 32, 64);
        if (half == 0) {
            atomicAdd(&s1l[lc], sp0);
            atomicAdd(&s1l[32 + lc], sp1);
        }
        // C/D layout: col=lane&31, row=(r&3)+8*(r>>2)+4*(lane>>5)  [m74/m101]
        #pragma unroll
        for (int r = 0; r < 16; ++r) {
            const int row = (r & 3) + 8 * (r >> 2) + 4 * half;
            atomicAdd(&Gl[row][lc],           a00[r]);
            atomicAdd(&Gl[row][32 + lc],      a01[r]);
            atomicAdd(&Gl[32 + row][lc],      a10[r]);
            atomicAdd(&Gl[32 + row][32 + lc], a11[r]);
        }
    }
    __syncthreads();

    // 64-dim recurrence (wave 0), write u to workspace
    if (tid < 64) {
        const int j = tid;
        const float s1j = s1l[j];
        float u = 0.f, rho = 0.f;
        for (int l = 0; l < NLAYER; ++l) {
            float dot = 0.f;
            #pragma unroll 8
            for (int k2 = 0; k2 < DD; ++k2) dot += Gl[j][k2] * ul[k2];
            const float s = s1j + dot;
            rho = gam[l] * rho + (qsl[l] * (1.0f / (float)NN)) * s;
            u += alp[l] * rho;
            ul[j] = u;   // wave-lockstep, in-order LDS per wave
        }
        uws[(long)blockIdx.x * DD + j] = u;
    }
}

// ---- Kernel B: xu[n] = X[n]·u, then float4 copy with col-64 patch ----
__global__ __launch_bounds__(1024)
void kernB(const float* __restrict__ Zin,
           const float* __restrict__ uws,
           float* __restrict__ out) {
    __shared__ float us[DD];
    __shared__ float xu[NROW];

    const int tid  = threadIdx.x;
    const int w    = tid >> 6;          // 16 waves
    const int lane = tid & 63;
    const long base = (long)blockIdx.x * TOT;

    if (tid < DD) us[tid] = uws[(long)blockIdx.x * DD + tid];
    __syncthreads();

    // phase 1: per-wave row dots (cols 0..63 coalesced; 4 rows in flight)
    {
        const float ucol = us[lane];
        int n = w;
        for (; n + 48 < NROW; n += 64) {
            float p0 = Zin[base + (long)(n     ) * NCOL + lane] * ucol;
            float p1 = Zin[base + (long)(n + 16) * NCOL + lane] * ucol;
            float p2 = Zin[base + (long)(n + 32) * NCOL + lane] * ucol;
            float p3 = Zin[base + (long)(n + 48) * NCOL + lane] * ucol;
            #pragma unroll
            for (int off = 32; off > 0; off >>= 1) {
                p0 += __shfl_xor(p0, off, 64);
                p1 += __shfl_xor(p1, off, 64);
                p2 += __shfl_xor(p2, off, 64);
                p3 += __shfl_xor(p3, off, 64);
            }
            if (lane == 0) {
                xu[n] = p0; xu[n + 16] = p1; xu[n + 32] = p2; xu[n + 48] = p3;
            }
        }
        for (; n < NROW; n += 16) {
            float p = Zin[base + (long)n * NCOL + lane] * ucol;
            #pragma unroll
            for (int off = 32; off > 0; off >>= 1) p += __shfl_xor(p, off, 64);
            if (lane == 0) xu[n] = p;
        }
    }
    __syncthreads();

    // phase 2: aligned float4 copy, patch col 64 in-register (full-line writes)
    {
        const long gbeg = base, gend = base + TOT;
        const int  c    = (int)((4 - (base & 3)) & 3);
        const long abeg = gbeg + c;
        const int  tc   = (int)(gend & 3);
        const long aend = gend - tc;
        const int  nvec = (int)((aend - abeg) >> 2);

        #pragma unroll
        for (int k = 0; k < 9; ++k) {
            const int u = tid + k * 1024;
            if (u < nvec) {
                const long a = abeg + (long)u * 4;
                float4 v = *(const float4*)(Zin + a);
                const int li = (int)(a - base);
                const int j  = li % NCOL;            // col of component 0
                if (j >= NCOL - 4) {                 // contains col 64
                    const int comp = DD - j;         // 0..3
                    const float pv = xu[(li + comp) / NCOL];
                    if      (comp == 0) v.x += pv;
                    else if (comp == 1) v.y += pv;
                    else if (comp == 2) v.z += pv;
                    else                v.w += pv;
                }
                *(float4*)(out + a) = v;
            }
        }
        if (tid < c) {                               // head scalars
            const long g = gbeg + tid;
            const int li = (int)(g - base);
            float v = Zin[g];
            if (li % NCOL == DD) v += xu[li / NCOL];
            out[g] = v;
        }
        if (tc && tid >= 64 && tid < 64 + tc) {      // tail scalars
            const long g = aend + (tid - 64);
            const int li = (int)(g - base);
            float v = Zin[g];
            if (li % NCOL == DD) v += xu[li / NCOL];
            out[g] = v;
        }
    }
}

extern "C" void kernel_launch(void* const* d_in, const int* in_sizes, int n_in,
                              void* d_out, int out_size, void* d_ws, size_t ws_size,
                              hipStream_t stream) {
    const float* Z        = (const float*)d_in[0];
    const float* allparam = (const float*)d_in[1];
    const float* gam      = (const float*)d_in[2];
    const float* alp      = (const float*)d_in[3];
    float* outp = (float*)d_out;
    float* uws  = (float*)d_ws;   // 512*64 floats = 128 KB
    kernA<<<dim3(512), dim3(512),  0, stream>>>(Z, allparam, gam, alp, uws);
    kernB<<<dim3(512), dim3(1024), 0, stream>>>(Z, uws, outp);
}